// Round 1
// baseline (3366.601 us; speedup 1.0000x reference)
//
#include <hip/hip_runtime.h>

// Problem constants (match reference)
constexpr int NY = 384, NX = 384, S = 4, NSRC = 1, NREC = 96, NT = 600;
constexpr int NN = NY * NX;          // cells per shot
constexpr int PML = 20;
// d0 = 3*2500*ln(1000)/(2*20*4.0) computed in double, rounded at use (matches numpy->f32 path)
constexpr float D0 = 323.80102870228766f;
constexpr float HALF_DT = 0.00025f;  // 0.5*DT
constexpr float DT2 = 2.5e-7f;       // DT*DT
constexpr float C0 = -1.0f / 12.0f, C1 = 4.0f / 3.0f, C2 = -2.5f;
constexpr float INV_DX2 = 0.0625f;   // 1/(DX*DX) = 1/16, exact

__global__ __launch_bounds__(256) void init_kernel(
    const float* __restrict__ vp,
    float* __restrict__ v2dt2, float* __restrict__ aArr, float* __restrict__ bArr)
{
    int i = blockIdx.x * 256 + threadIdx.x;
    if (i >= NN) return;
    int x = i % NX, y = i / NX;

    float yf = (float)y, xf = (float)x;
    float ly = fmaxf((20.0f - yf) / 20.0f, 0.0f);
    float ry = fmaxf((yf - 363.0f) / 20.0f, 0.0f);
    float my = fmaxf(ly, ry);
    float sig_y = D0 * my * my;
    float lx = fmaxf((20.0f - xf) / 20.0f, 0.0f);
    float rx = fmaxf((xf - 363.0f) / 20.0f, 0.0f);
    float mx = fmaxf(lx, rx);
    float sig_x = D0 * mx * mx;
    float sig = sig_y + sig_x;

    float v = vp[i];
    v2dt2[i] = (v * v) * DT2;
    aArr[i] = 1.0f + HALF_DT * sig;
    bArr[i] = 1.0f - HALF_DT * sig;
}

// One leapfrog step for all S*NY*NX cells.
// Also: thread at source cell injects source; first S*NREC threads record
// receivers for the PREVIOUS step (u_cur == u_next of step t-1, fully written).
__global__ __launch_bounds__(256) void step_kernel(
    const float* __restrict__ u_prev, const float* __restrict__ u_cur,
    float* __restrict__ u_next,
    const float* __restrict__ v2dt2, const float* __restrict__ aArr,
    const float* __restrict__ bArr,
    const float* __restrict__ src_amp,   // [S, NT] (NSRC=1)
    const int* __restrict__ src_loc,     // [S, 2]
    const int* __restrict__ rec_loc,     // [S*NREC, 2]
    float* __restrict__ out,             // [S*NREC, NT]
    int t)
{
    int idx = blockIdx.x * 256 + threadIdx.x;

    // fused receiver recording for step t-1
    if (t > 0 && idx < S * NREC) {
        int s = idx / NREC;
        int ryy = rec_loc[idx * 2], rxx = rec_loc[idx * 2 + 1];
        out[idx * NT + (t - 1)] = u_cur[s * NN + ryy * NX + rxx];
    }

    int x = idx % NX;
    int yz = idx / NX;
    int y = yz % NY;
    int s = yz / NY;

    const float* u = u_cur + s * NN;
    int c = y * NX + x;

    float uc  = u[c];
    float ym1 = (y >= 1)      ? u[c - NX]     : 0.0f;
    float ym2 = (y >= 2)      ? u[c - 2 * NX] : 0.0f;
    float yp1 = (y <= NY - 2) ? u[c + NX]     : 0.0f;
    float yp2 = (y <= NY - 3) ? u[c + 2 * NX] : 0.0f;
    float xm1 = (x >= 1)      ? u[c - 1]      : 0.0f;
    float xm2 = (x >= 2)      ? u[c - 2]      : 0.0f;
    float xp1 = (x <= NX - 2) ? u[c + 1]      : 0.0f;
    float xp2 = (x <= NX - 3) ? u[c + 2]      : 0.0f;

    float lyv = C0 * (ym2 + yp2) + C1 * (ym1 + yp1) + C2 * uc;
    float lxv = C0 * (xm2 + xp2) + C1 * (xm1 + xp1) + C2 * uc;
    float lap = (lyv + lxv) * INV_DX2;

    float num = 2.0f * uc - bArr[c] * u_prev[s * NN + c] + v2dt2[c] * lap;
    float un = num / aArr[c];

    int sy = src_loc[s * 2], sx = src_loc[s * 2 + 1];
    if (y == sy && x == sx) {
        un += src_amp[s * NT + t] * v2dt2[c];
    }
    u_next[s * NN + c] = un;
}

__global__ void record_kernel(const float* __restrict__ u,
                              const int* __restrict__ rec_loc,
                              float* __restrict__ out, int t)
{
    int idx = blockIdx.x * blockDim.x + threadIdx.x;
    if (idx >= S * NREC) return;
    int s = idx / NREC;
    int ryy = rec_loc[idx * 2], rxx = rec_loc[idx * 2 + 1];
    out[idx * NT + t] = u[s * NN + ryy * NX + rxx];
}

extern "C" void kernel_launch(void* const* d_in, const int* in_sizes, int n_in,
                              void* d_out, int out_size, void* d_ws, size_t ws_size,
                              hipStream_t stream)
{
    const float* vp      = (const float*)d_in[0];
    const float* src_amp = (const float*)d_in[1];
    const int*   src_loc = (const int*)d_in[2];
    const int*   rec_loc = (const int*)d_in[3];
    float* out = (float*)d_out;

    float* ws = (float*)d_ws;
    float* uA = ws;                 // S*NN
    float* uB = uA + S * NN;        // S*NN
    float* v2 = uB + S * NN;        // NN
    float* aA = v2 + NN;            // NN
    float* bA = aA + NN;            // NN

    // zero wavefields every call (d_ws is poisoned once and never re-poisoned)
    hipMemsetAsync(uA, 0, (size_t)(2 * S * NN) * sizeof(float), stream);

    init_kernel<<<(NN + 255) / 256, 256, 0, stream>>>(vp, v2, aA, bA);

    float* up = uA;   // u_prev
    float* uc = uB;   // u_cur
    for (int t = 0; t < NT; ++t) {
        float* un = up;  // write u_next over u_prev (in-place safe: own-cell read only)
        step_kernel<<<(S * NN) / 256, 256, 0, stream>>>(
            up, uc, un, v2, aA, bA, src_amp, src_loc, rec_loc, out, t);
        up = uc;
        uc = un;
    }
    // record receivers for the final step
    record_kernel<<<2, 192, 0, stream>>>(uc, rec_loc, out, NT - 1);
}